// Round 14
// baseline (10123.598 us; speedup 1.0000x reference)
//
#include <hip/hip_runtime.h>
#include <hip/hip_bf16.h>
#include <cstdint>
#include <cstddef>

#define T_DIM 512
#define B_DIM 256
#define D_DIM 256
#define H_DIM 512
#define O_DIM 256
#define NSTEP 10
#define WIN 16
#define PFX 6   // W units per k-half resident in LDS (6*2*512*16B = 96 KB)
#define STAGGER_TICKS 33   // 0.33 us per slot at 100 MHz; 32 slots ~ one pass

__device__ __forceinline__ unsigned short f2bf(float f) {
    __hip_bfloat16 b = __float2bfloat16(f);   // RNE
    return *reinterpret_cast<unsigned short*>(&b);
}

// ---------------- prep: W float4-unit packing + transposes ----------------
__global__ void k_prep(const float* __restrict__ W_hh,
                       const float* __restrict__ W_ih,
                       const float* __restrict__ W_out,
                       float* __restrict__ whh4,   // [128][512] float4 units
                       float* __restrict__ wihT,   // [256][512] d-major
                       float* __restrict__ woutT)  // [512][256] h-major
{
    int idx = blockIdx.x * blockDim.x + threadIdx.x;
    if (idx < 65536) {
        int q = idx >> 9, h = idx & 511;
        ((float4*)whh4)[q * 512 + h] = ((const float4*)W_hh)[h * 128 + q];
    } else if (idx < 65536 + 131072) {
        int j = idx - 65536;
        int d = j >> 9, h = j & 511;
        wihT[d * 512 + h] = W_ih[h * 257 + d];   // W_ih row length = 257
    } else if (idx < 65536 + 131072 + 131072) {
        int j = idx - (65536 + 131072);
        int h = j >> 8, o = j & 255;
        woutT[h * 256 + o] = W_out[o * 512 + h];
    }
}

// ---------------- sequential ACT recurrence: 1 row/block + phase stagger ---
// Body byte-identical to r12 (LDS W prefix + dwordx4 stream + conditional
// barrier C). New: per-block start stagger. All blocks do near-identical work
// (steps ~= 2 for every (t,b)) so they run in lockstep: the 32 CUs of an XCD
// fire their 928 KB L2 streams simultaneously (instantaneous ~4.3 TB/s = the
// per-XCD L2 ceiling), then idle the L2 during their tails. Staggering block
// start phases by 0.33 us x ((bid>>3)&31) spreads the bursts across the pass
// period; sustained demand (~2.8 TB/s) is under the ceiling. Timing-only:
// outputs bitwise-identical.
__global__ __launch_bounds__(1024, 1) void k_recur13(
    const float* __restrict__ x,      // [T,B,256]
    const float* __restrict__ wihT,   // [256][512]
    const float* __restrict__ whh4,   // [128][512] float4 units
    const float* __restrict__ W_ih,   // flag col at [h*257+256]
    const float* __restrict__ w_halt,
    const float* __restrict__ b_ih,
    const float* __restrict__ b_hh,
    const float* __restrict__ b_halt,
    float* out,                       // d_out (y region reused as bf16 s_acc)
    float* __restrict__ psum_g)       // [T*B]
{
    __shared__ __align__(16) float4 wp_l[2 * PFX * 512];  // 96 KB W prefix
    __shared__ __align__(16) float sb[2][H_DIM];     // s ping-pong  4 KB
    __shared__ __align__(16) float xcw[WIN][H_DIM];  // xc window   32 KB
    __shared__ float prt1[H_DIM];                    // kh=1 partial  2 KB
    __shared__ __align__(16) float xst[WIN * D_DIM]; // staging     16 KB
    __shared__ float whalt_l[H_DIM];
    __shared__ float flag_l[H_DIM];
    __shared__ float bias_l[H_DIM];
    __shared__ float red[8];

    const int tid = threadIdx.x;
    const int h = tid & 511;
    const int kh = tid >> 9;
    const int b = blockIdx.x;
    const int wave = tid >> 6;       // kh=0 half: waves 0..7
    const int lane = tid & 63;

    // ---- phase stagger: desync the 32 blocks sharing each XCD L2 ----
    {
        const int slot = (b >> 3) & 31;   // bid%8 = XCD under round-robin
        if (slot) {
            const unsigned long long tgt =
                (unsigned long long)slot * STAGGER_TICKS;
            const unsigned long long c0 = __builtin_amdgcn_s_memrealtime();
            while (__builtin_amdgcn_s_memrealtime() - c0 < tgt) {}
        }
    }

    if (!kh) {
        whalt_l[h] = w_halt[h];
        flag_l[h] = W_ih[h * 257 + 256];
        bias_l[h] = b_ih[h] + b_hh[h];
        sb[0][h] = 0.f;
    }
    // stage W prefix: wp_l[kh2*PFX*512 + j*512 + h] = whh4 unit (kh2, j, h)
    for (int i = tid; i < 2 * PFX * 512; i += 1024) {
        const int kh2 = i / (PFX * 512);
        const int rem = i - kh2 * (PFX * 512);
        wp_l[i] = ((const float4*)whh4)[(size_t)kh2 * 64 * 512 + rem];
    }

    const float bh = b_halt[0];
    const float THR = 1.0f - 0.01f;
    unsigned short* sacc_out = (unsigned short*)out;
    float* rho_out = out + (size_t)T_DIM * B_DIM * O_DIM;
    float* n_out = rho_out + (size_t)T_DIM * B_DIM;

    const float4* w4 = (const float4*)whh4 + (size_t)kh * 64 * 512 + h;
    const float4* wp = &wp_l[kh * PFX * 512 + h];

    int t = 0, nst = 0, cur = 0;
    float hsum = 0.f, runf = 1.f, stepsf = 0.f, remf = 0.f, ps = 0.f;
    float sacc_v = 0.f;

#define DO_REFILL(TB)                                                         \
    {                                                                         \
        __syncthreads();                                                      \
        for (int i = tid; i < WIN * D_DIM; i += 1024)                         \
            xst[i] = x[((size_t)((TB) + (i >> 8)) * B_DIM + b) * D_DIM +      \
                       (i & 255)];                                            \
        __syncthreads();                                                      \
        float xa[8];                                                          \
        _Pragma("unroll") for (int jj = 0; jj < 8; ++jj) xa[jj] = 0.f;        \
        for (int d = 0; d < 256; d += 4) {                                    \
            const float u0 = wihT[(d + 0) * 512 + h];                         \
            const float u1 = wihT[(d + 1) * 512 + h];                         \
            const float u2 = wihT[(d + 2) * 512 + h];                         \
            const float u3 = wihT[(d + 3) * 512 + h];                         \
            _Pragma("unroll") for (int jj = 0; jj < 8; ++jj) {                \
                const float4 xv =                                             \
                    *(const float4*)&xst[(kh * 8 + jj) * 256 + d];            \
                xa[jj] += xv.x * u0;                                          \
                xa[jj] += xv.y * u1;                                          \
                xa[jj] += xv.z * u2;                                          \
                xa[jj] += xv.w * u3;                                          \
            }                                                                 \
        }                                                                     \
        _Pragma("unroll") for (int jj = 0; jj < 8; ++jj)                      \
            xcw[kh * 8 + jj][h] = xa[jj] + bias_l[h];                         \
        __syncthreads();                                                      \
    }

    DO_REFILL(0)   // leading __syncthreads also covers wp_l/sb/bias staging

    for (;;) {
        // ---- phase 1: W stream (LDS prefix j<PFX, L2 j>=PFX) x s ----
        const float4* s4 = (const float4*)&sb[cur][kh << 8];
        float4 A[4];
#pragma unroll
        for (int c = 0; c < 4; ++c) A[c] = float4{0.f, 0.f, 0.f, 0.f};
#pragma unroll
        for (int j = 0; j < PFX; ++j) {
            const int c = j & 3;
            const float4 wv = wp[j * 512];
            const float4 sv = s4[j];
            A[c].x += sv.x * wv.x;
            A[c].y += sv.y * wv.y;
            A[c].z += sv.z * wv.z;
            A[c].w += sv.w * wv.w;
        }
#pragma unroll 8
        for (int j = PFX; j < 64; ++j) {
            const int c = j & 3;
            const float4 wv = w4[(size_t)j * 512];
            const float4 sv = s4[j];
            A[c].x += sv.x * wv.x;
            A[c].y += sv.y * wv.y;
            A[c].z += sv.z * wv.z;
            A[c].w += sv.w * wv.w;
        }
        const float g0 = (A[0].x + A[0].y) + (A[0].z + A[0].w);
        const float g1 = (A[1].x + A[1].y) + (A[1].z + A[1].w);
        const float g2 = (A[2].x + A[2].y) + (A[2].z + A[2].w);
        const float g3 = (A[3].x + A[3].y) + (A[3].z + A[3].w);
        const float pd = (g0 + g1) + (g2 + g3);

        if (kh) prt1[h] = pd;
        __syncthreads();   // A: kh=1 partial ready; sb[cur] fully consumed

        // ---- phase 2: kh=0 half post-processes the row ----
        float sn = 0.f;
        if (!kh) {
            float base = xcw[t & (WIN - 1)][h];
            if (nst == 0) base += flag_l[h];
            const float pre = (base + pd) + prt1[h];
            sn = tanhf(pre);
            sb[cur ^ 1][h] = sn;
            float pt = sn * whalt_l[h];
#pragma unroll
            for (int m = 1; m < 64; m <<= 1) pt += __shfl_xor(pt, m, 64);
            if (lane == 0) red[wave] = pt;
        }
        __syncthreads();   // B: s-next + red ready

        // ---- phase 3: halting scalars, replicated on all threads ----
        const float dotv = ((red[0] + red[1]) + (red[2] + red[3])) +
                           ((red[4] + red[5]) + (red[6] + red[7]));
        const float z = dotv + bh;
        const float hn = 1.f / (1.f + expf(-z));
        const float ns = hsum + hn;
        const float stop = (ns >= THR) ? runf : 0.f;
        const float still = runf - stop;
        const float rem = (1.f - hsum) * stop;
        const float p = hn * still + rem;
        ps += p;
        stepsf += runf;   // old running, matches reference order
        remf += rem;
        hsum = ns;
        runf = still;
        nst += 1;
        if (!kh) sacc_v += p * sn;
        cur ^= 1;
        const int adv = (still == 0.f) || (nst == NSTEP);

        // ---- phase 4: advance (barrier only on adv) ----
        if (adv) {
            if (!kh) {
                sb[cur][h] = sacc_v;   // s(next t) = s_acc
                sacc_out[((size_t)t * B_DIM + b) * (size_t)H_DIM + h] =
                    f2bf(sacc_v);
            }
            if (tid == 0) {
                const int bi = t * B_DIM + b;
                psum_g[bi] = ps;
                rho_out[bi] = stepsf + remf;
                n_out[bi] = stepsf;
            }
            hsum = 0.f; runf = 1.f; stepsf = 0.f; remf = 0.f; ps = 0.f;
            nst = 0; sacc_v = 0.f;
            t += 1;
            __syncthreads();   // C: sacc overwrite of sb visible to all
            if (t == T_DIM) break;                    // uniform
            if ((t & (WIN - 1)) == 0) DO_REFILL(t)
        }
    }
#undef DO_REFILL
}

// ---------------- y = s_acc @ W_out.T + psum * b_out ----------------
__global__ __launch_bounds__(256) void k_y(
    const float* __restrict__ woutT,  // [512][256]
    const float* __restrict__ b_out,
    const float* __restrict__ psum_g,
    float* out)
{
    __shared__ float sl[16][512];
    __shared__ float pl[16];
    const int tid = threadIdx.x;
    const int tb0 = blockIdx.x * 16;
    const unsigned short* sacc = (const unsigned short*)out;
    for (int i = tid; i < 16 * 512; i += 256) {
        unsigned int u = sacc[(size_t)tb0 * 512 + i];
        u <<= 16;
        sl[i >> 9][i & 511] = __uint_as_float(u);
    }
    if (tid < 16) pl[tid] = psum_g[tb0 + tid];
    __syncthreads();
    const int o = tid;
    float acc[16];
#pragma unroll
    for (int r = 0; r < 16; ++r) acc[r] = 0.f;
    for (int hh = 0; hh < 512; hh += 4) {
        const float wv0 = woutT[(hh + 0) * 256 + o];
        const float wv1 = woutT[(hh + 1) * 256 + o];
        const float wv2 = woutT[(hh + 2) * 256 + o];
        const float wv3 = woutT[(hh + 3) * 256 + o];
#pragma unroll
        for (int r = 0; r < 16; ++r) {
            const float4 sv = *(const float4*)&sl[r][hh];
            acc[r] += sv.x * wv0;
            acc[r] += sv.y * wv1;
            acc[r] += sv.z * wv2;
            acc[r] += sv.w * wv3;
        }
    }
    const float bo = b_out[o];
    for (int r = 0; r < 16; ++r)
        out[(size_t)(tb0 + r) * 256 + o] = acc[r] + pl[r] * bo;
}

extern "C" void kernel_launch(void* const* d_in, const int* in_sizes, int n_in,
                              void* d_out, int out_size, void* d_ws, size_t ws_size,
                              hipStream_t stream) {
    const float* x = (const float*)d_in[0];
    const float* W_ih = (const float*)d_in[1];
    const float* b_ih = (const float*)d_in[2];
    const float* W_hh = (const float*)d_in[3];
    const float* b_hh = (const float*)d_in[4];
    const float* W_halt = (const float*)d_in[5];
    const float* b_halt = (const float*)d_in[6];
    const float* W_out = (const float*)d_in[7];
    const float* b_out = (const float*)d_in[8];
    float* out = (float*)d_out;

    char* ws = (char*)d_ws;
    float* whh4 = (float*)ws;                                 // 1 MB
    float* wihT = (float*)(ws + (1u << 20));                  // 512 KB
    float* woutT = (float*)(ws + (1u << 20) + (512u << 10));  // 512 KB
    float* psum = (float*)(ws + (2u << 20));                  // 512 KB

    hipLaunchKernelGGL(k_prep, dim3(1284), dim3(256), 0, stream,
                       W_hh, W_ih, W_out, whh4, wihT, woutT);
    hipLaunchKernelGGL(k_recur13, dim3(B_DIM), dim3(1024), 0, stream,
                       x, wihT, whh4, W_ih, W_halt, b_ih, b_hh, b_halt,
                       out, psum);
    hipLaunchKernelGGL(k_y, dim3((T_DIM * B_DIM) / 16), dim3(256), 0, stream,
                       woutT, b_out, psum, out);
}

// Round 15
// 9974.180 us; speedup vs baseline: 1.0150x; 1.0150x over previous
//
#include <hip/hip_runtime.h>
#include <hip/hip_bf16.h>
#include <cstdint>
#include <cstddef>

#define T_DIM 512
#define B_DIM 256
#define D_DIM 256
#define H_DIM 512
#define O_DIM 256
#define NSTEP 10
#define WIN 16
#define PFX 5   // W units per k-half in LDS (2*5*512*16B = 80 KB)

__device__ __forceinline__ unsigned short f2bf(float f) {
    __hip_bfloat16 b = __float2bfloat16(f);   // RNE
    return *reinterpret_cast<unsigned short*>(&b);
}

// ---------------- prep: W float4-unit packing + transposes ----------------
// whh4 unit layout: ((float4*)whh4)[q*512+h]
//   = float4{ W_hh[h][4q], W_hh[h][4q+1], W_hh[h][4q+2], W_hh[h][4q+3] }
__global__ void k_prep(const float* __restrict__ W_hh,
                       const float* __restrict__ W_ih,
                       const float* __restrict__ W_out,
                       float* __restrict__ whh4,   // [128][512] float4 units
                       float* __restrict__ wihT,   // [256][512] d-major
                       float* __restrict__ woutT)  // [512][256] h-major
{
    int idx = blockIdx.x * blockDim.x + threadIdx.x;
    if (idx < 65536) {
        int q = idx >> 9, h = idx & 511;
        ((float4*)whh4)[q * 512 + h] = ((const float4*)W_hh)[h * 128 + q];
    } else if (idx < 65536 + 131072) {
        int j = idx - 65536;
        int d = j >> 9, h = j & 511;
        wihT[d * 512 + h] = W_ih[h * 257 + d];   // W_ih row length = 257
    } else if (idx < 65536 + 131072 + 131072) {
        int j = idx - (65536 + 131072);
        int h = j >> 8, o = j & 255;
        woutT[h * 256 + o] = W_out[o * 512 + h];
    }
}

// ---------------- sequential ACT recurrence: 4-way k-split ----------------
// 256 blocks x 1024 threads; block b owns batch row b. NEW partition: thread
// (qk = tid>>8, h2 = tid&255) computes k-quarter [128qk,128qk+128) for TWO
// columns h2 and h2+256. Per-thread FMAs unchanged (256) and W bytes
// unchanged (2nd column = offset:4096 on the same address), but each thread
// reads only 128 s values -> s-broadcast DS traffic HALVES (1 MB -> 512 KB
// per pass), removing the DS pipe as a co-bottleneck with the L2 port.
// Column combine is now 4 partials: pre = (base + (p0+p1)) + (p2+p3).
__global__ __launch_bounds__(1024, 1) void k_recur14(
    const float* __restrict__ x,      // [T,B,256]
    const float* __restrict__ wihT,   // [256][512]
    const float* __restrict__ whh4,   // [128][512] float4 units
    const float* __restrict__ W_ih,   // flag col at [h*257+256]
    const float* __restrict__ w_halt,
    const float* __restrict__ b_ih,
    const float* __restrict__ b_hh,
    const float* __restrict__ b_halt,
    float* out,                       // d_out (y region reused as bf16 s_acc)
    float* __restrict__ psum_g)       // [T*B]
{
    __shared__ __align__(16) float4 wp_l[2 * PFX * 512];  // 80 KB W prefix
    __shared__ __align__(16) float sb[2][H_DIM];     // s ping-pong  4 KB
    __shared__ __align__(16) float xcw[WIN][H_DIM];  // xc window   32 KB
    __shared__ float prt[4][H_DIM];                  // partials      8 KB
    __shared__ __align__(16) float xst[WIN * D_DIM]; // staging     16 KB
    __shared__ float whalt_l[H_DIM];
    __shared__ float flag_l[H_DIM];
    __shared__ float bias_l[H_DIM];
    __shared__ float red[8];

    const int tid = threadIdx.x;
    const int h = tid & 511;     // refill mapping (token-identical to r12)
    const int khr = tid >> 9;    // refill k-half
    const int h2 = tid & 255;    // column base (stream mapping)
    const int qk = tid >> 8;     // k-quarter 0..3 (wave-uniform)
    const int b = blockIdx.x;
    const int wave = tid >> 6;
    const int lane = tid & 63;

    if (tid < 512) {
        whalt_l[tid] = w_halt[tid];
        flag_l[tid] = W_ih[tid * 257 + 256];
        bias_l[tid] = b_ih[tid] + b_hh[tid];
        sb[0][tid] = 0.f;
    }
    // stage W prefix: wp_l[kh2*PFX*512 + j*512 + h] = whh4 unit (kh2*64+j, h)
    for (int i = tid; i < 2 * PFX * 512; i += 1024) {
        const int kh2 = i / (PFX * 512);
        const int rem = i - kh2 * (PFX * 512);
        wp_l[i] = ((const float4*)whh4)[(size_t)kh2 * 64 * 512 + rem];
    }

    const float bh = b_halt[0];
    const float THR = 1.0f - 0.01f;
    unsigned short* sacc_out = (unsigned short*)out;
    float* rho_out = out + (size_t)T_DIM * B_DIM * O_DIM;
    float* n_out = rho_out + (size_t)T_DIM * B_DIM;

    // L2 W pointer: unit i of this quarter at wL2[i*512] (col h2) and
    // wL2[i*512+256] (col h2+256, same address + imm offset 4096 B).
    const float4* wL2 = (const float4*)whh4 + (size_t)qk * 32 * 512 + h2;
    // prefix (quarters 0 and 2 only = first PFX units of each k-half)
    const float4* wpB = &wp_l[(qk >> 1) * PFX * 512 + h2];
    const bool haspfx = (qk & 1) == 0;   // wave-uniform branch

    int t = 0, nst = 0, cur = 0;
    float hsum = 0.f, runf = 1.f, stepsf = 0.f, remf = 0.f, ps = 0.f;
    float sacc_v = 0.f;   // tid<512: column tid accumulator

#define DO_REFILL(TB)                                                         \
    {                                                                         \
        __syncthreads();                                                      \
        for (int i = tid; i < WIN * D_DIM; i += 1024)                         \
            xst[i] = x[((size_t)((TB) + (i >> 8)) * B_DIM + b) * D_DIM +      \
                       (i & 255)];                                            \
        __syncthreads();                                                      \
        float xa[8];                                                          \
        _Pragma("unroll") for (int jj = 0; jj < 8; ++jj) xa[jj] = 0.f;        \
        for (int d = 0; d < 256; d += 4) {                                    \
            const float u0 = wihT[(d + 0) * 512 + h];                         \
            const float u1 = wihT[(d + 1) * 512 + h];                         \
            const float u2 = wihT[(d + 2) * 512 + h];                         \
            const float u3 = wihT[(d + 3) * 512 + h];                         \
            _Pragma("unroll") for (int jj = 0; jj < 8; ++jj) {                \
                const float4 xv =                                             \
                    *(const float4*)&xst[(khr * 8 + jj) * 256 + d];           \
                xa[jj] += xv.x * u0;                                          \
                xa[jj] += xv.y * u1;                                          \
                xa[jj] += xv.z * u2;                                          \
                xa[jj] += xv.w * u3;                                          \
            }                                                                 \
        }                                                                     \
        _Pragma("unroll") for (int jj = 0; jj < 8; ++jj)                      \
            xcw[khr * 8 + jj][h] = xa[jj] + bias_l[h];                        \
        __syncthreads();                                                      \
    }

// one k-unit: chain c = i&3; cols A (h2) and B (h2+256) elementwise x,y,z,w
#define KFMA(WA, WB, i)                                                       \
    {                                                                         \
        const int c = (i) & 3;                                                \
        const float4 sv = s4[(i)];                                            \
        A[c].x += sv.x * (WA).x; A[c].y += sv.y * (WA).y;                     \
        A[c].z += sv.z * (WA).z; A[c].w += sv.w * (WA).w;                     \
        Bc[c].x += sv.x * (WB).x; Bc[c].y += sv.y * (WB).y;                   \
        Bc[c].z += sv.z * (WB).z; Bc[c].w += sv.w * (WB).w;                   \
    }

    DO_REFILL(0)   // leading __syncthreads also covers wp_l/sb/bias staging

    for (;;) {
        // ---- phase 1: W stream x s-quarter broadcast, 2 columns ----
        const float4* s4 = (const float4*)&sb[cur][qk << 7];
        float4 A[4], Bc[4];
#pragma unroll
        for (int c = 0; c < 4; ++c) {
            A[c] = float4{0.f, 0.f, 0.f, 0.f};
            Bc[c] = float4{0.f, 0.f, 0.f, 0.f};
        }
        if (haspfx) {
#pragma unroll
            for (int i = 0; i < PFX; ++i) {
                const float4 wvA = wpB[i * 512];
                const float4 wvB = wpB[i * 512 + 256];
                KFMA(wvA, wvB, i)
            }
#pragma unroll 4
            for (int i = PFX; i < 32; ++i) {
                const float4 wvA = wL2[(size_t)i * 512];
                const float4 wvB = wL2[(size_t)i * 512 + 256];
                KFMA(wvA, wvB, i)
            }
        } else {
#pragma unroll 4
            for (int i = 0; i < 32; ++i) {
                const float4 wvA = wL2[(size_t)i * 512];
                const float4 wvB = wL2[(size_t)i * 512 + 256];
                KFMA(wvA, wvB, i)
            }
        }
        {
            const float a0 = (A[0].x + A[0].y) + (A[0].z + A[0].w);
            const float a1 = (A[1].x + A[1].y) + (A[1].z + A[1].w);
            const float a2 = (A[2].x + A[2].y) + (A[2].z + A[2].w);
            const float a3 = (A[3].x + A[3].y) + (A[3].z + A[3].w);
            prt[qk][h2] = (a0 + a1) + (a2 + a3);
        }
        {
            const float a0 = (Bc[0].x + Bc[0].y) + (Bc[0].z + Bc[0].w);
            const float a1 = (Bc[1].x + Bc[1].y) + (Bc[1].z + Bc[1].w);
            const float a2 = (Bc[2].x + Bc[2].y) + (Bc[2].z + Bc[2].w);
            const float a3 = (Bc[3].x + Bc[3].y) + (Bc[3].z + Bc[3].w);
            prt[qk][h2 + 256] = (a0 + a1) + (a2 + a3);
        }
        __syncthreads();   // A: all 4 quarter-partials ready; sb consumed

        // ---- phase 2: tid<512 post-processes column tid ----
        float sn = 0.f;
        if (tid < 512) {
            float base = xcw[t & (WIN - 1)][tid];
            if (nst == 0) base += flag_l[tid];
            const float p01 = prt[0][tid] + prt[1][tid];
            const float p23 = prt[2][tid] + prt[3][tid];
            const float pre = (base + p01) + p23;
            sn = tanhf(pre);
            sb[cur ^ 1][tid] = sn;
            float pt = sn * whalt_l[tid];
#pragma unroll
            for (int m = 1; m < 64; m <<= 1) pt += __shfl_xor(pt, m, 64);
            if (lane == 0) red[wave] = pt;
        }
        __syncthreads();   // B: s-next + red ready

        // ---- phase 3: halting scalars, replicated on all threads ----
        const float dotv = ((red[0] + red[1]) + (red[2] + red[3])) +
                           ((red[4] + red[5]) + (red[6] + red[7]));
        const float z = dotv + bh;
        const float hn = 1.f / (1.f + expf(-z));
        const float ns = hsum + hn;
        const float stop = (ns >= THR) ? runf : 0.f;
        const float still = runf - stop;
        const float rem = (1.f - hsum) * stop;
        const float p = hn * still + rem;
        ps += p;
        stepsf += runf;   // old running, matches reference order
        remf += rem;
        hsum = ns;
        runf = still;
        nst += 1;
        if (tid < 512) sacc_v += p * sn;
        cur ^= 1;
        const int adv = (still == 0.f) || (nst == NSTEP);

        // ---- phase 4: advance (barrier only on adv; r11/r12-proven) ----
        if (adv) {
            if (tid < 512) {
                sb[cur][tid] = sacc_v;   // s(next t) = s_acc
                sacc_out[((size_t)t * B_DIM + b) * (size_t)H_DIM + tid] =
                    f2bf(sacc_v);
            }
            if (tid == 0) {
                const int bi = t * B_DIM + b;
                psum_g[bi] = ps;
                rho_out[bi] = stepsf + remf;
                n_out[bi] = stepsf;
            }
            hsum = 0.f; runf = 1.f; stepsf = 0.f; remf = 0.f; ps = 0.f;
            nst = 0; sacc_v = 0.f;
            t += 1;
            __syncthreads();   // C: sacc overwrite of sb visible to all
            if (t == T_DIM) break;                    // uniform
            if ((t & (WIN - 1)) == 0) DO_REFILL(t)
        }
    }
#undef DO_REFILL
#undef KFMA
}

// ---------------- y = s_acc @ W_out.T + psum * b_out ----------------
__global__ __launch_bounds__(256) void k_y(
    const float* __restrict__ woutT,  // [512][256]
    const float* __restrict__ b_out,
    const float* __restrict__ psum_g,
    float* out)
{
    __shared__ float sl[16][512];
    __shared__ float pl[16];
    const int tid = threadIdx.x;
    const int tb0 = blockIdx.x * 16;
    const unsigned short* sacc = (const unsigned short*)out;
    for (int i = tid; i < 16 * 512; i += 256) {
        unsigned int u = sacc[(size_t)tb0 * 512 + i];
        u <<= 16;
        sl[i >> 9][i & 511] = __uint_as_float(u);
    }
    if (tid < 16) pl[tid] = psum_g[tb0 + tid];
    __syncthreads();
    const int o = tid;
    float acc[16];
#pragma unroll
    for (int r = 0; r < 16; ++r) acc[r] = 0.f;
    for (int hh = 0; hh < 512; hh += 4) {
        const float wv0 = woutT[(hh + 0) * 256 + o];
        const float wv1 = woutT[(hh + 1) * 256 + o];
        const float wv2 = woutT[(hh + 2) * 256 + o];
        const float wv3 = woutT[(hh + 3) * 256 + o];
#pragma unroll
        for (int r = 0; r < 16; ++r) {
            const float4 sv = *(const float4*)&sl[r][hh];
            acc[r] += sv.x * wv0;
            acc[r] += sv.y * wv1;
            acc[r] += sv.z * wv2;
            acc[r] += sv.w * wv3;
        }
    }
    const float bo = b_out[o];
    for (int r = 0; r < 16; ++r)
        out[(size_t)(tb0 + r) * 256 + o] = acc[r] + pl[r] * bo;
}

extern "C" void kernel_launch(void* const* d_in, const int* in_sizes, int n_in,
                              void* d_out, int out_size, void* d_ws, size_t ws_size,
                              hipStream_t stream) {
    const float* x = (const float*)d_in[0];
    const float* W_ih = (const float*)d_in[1];
    const float* b_ih = (const float*)d_in[2];
    const float* W_hh = (const float*)d_in[3];
    const float* b_hh = (const float*)d_in[4];
    const float* W_halt = (const float*)d_in[5];
    const float* b_halt = (const float*)d_in[6];
    const float* W_out = (const float*)d_in[7];
    const float* b_out = (const float*)d_in[8];
    float* out = (float*)d_out;

    char* ws = (char*)d_ws;
    float* whh4 = (float*)ws;                                 // 1 MB
    float* wihT = (float*)(ws + (1u << 20));                  // 512 KB
    float* woutT = (float*)(ws + (1u << 20) + (512u << 10));  // 512 KB
    float* psum = (float*)(ws + (2u << 20));                  // 512 KB

    hipLaunchKernelGGL(k_prep, dim3(1284), dim3(256), 0, stream,
                       W_hh, W_ih, W_out, whh4, wihT, woutT);
    hipLaunchKernelGGL(k_recur14, dim3(B_DIM), dim3(1024), 0, stream,
                       x, wihT, whh4, W_ih, W_halt, b_ih, b_hh, b_halt,
                       out, psum);
    hipLaunchKernelGGL(k_y, dim3((T_DIM * B_DIM) / 16), dim3(256), 0, stream,
                       woutT, b_out, psum, out);
}